// Round 8
// baseline (89.188 us; speedup 1.0000x reference)
//
#include <hip/hip_runtime.h>
#include <math.h>

#define Bn 256
#define Dm 256
#define Hm 512
#define Em 64
#define NL 1024
#define TOPK 10
#define GS 8          // samples per expert group
#define MAXG 88       // max groups: 64 + (256-64)/8

// ============ K-split x4 dense: blockIdx.z = K-quarter -> writes its OWN buffer ============
// Y quarter buffers contiguous: Y + kq*Bn*OUT. Consumers add the 4 quarters.
// Input X has XPARTS part-buffers (stride Bn*IN) added at staging, with optional
// bias+relu of the previous layer (Bin != nullptr). zctr: if non-null, block (0,0,0)
// re-zeroes the root3 completion counter (device-scope atomic store).
template<int IN, int OUT, int MT, int XPARTS, bool GROUPED>
__global__ __launch_bounds__(512) void dense_ks4(
        const float* __restrict__ X, const int* __restrict__ perm,
        const float* __restrict__ Bin, int bin_estride,
        const float* __restrict__ W, const int4* __restrict__ groups,
        int* zctr, float* __restrict__ Y) {
    constexpr int NW = 8, KQ = IN / 4, KCH = KQ / NW, CCH = 256, NR = 4;

    if (zctr && threadIdx.x == 0 && blockIdx.x == 0 && blockIdx.y == 0 && blockIdx.z == 0)
        atomicExch(zctr, 0);

    int e, p0, cnt;
    if (GROUPED) {
        const int4 g = groups[blockIdx.x];
        if (g.z == 0) return;
        e = g.x; p0 = g.y; cnt = g.z;
    } else {
        e = 0; p0 = blockIdx.x * MT; cnt = MT;
    }
    const int kq = blockIdx.z;          // 0..3
    const int kbase = kq * KQ;

    __shared__ float sxT[KQ * MT];      // [local i][c]
    __shared__ float part[NR * MT * CCH];
    const int tid = threadIdx.x;

    // stage activations (sum XPARTS part-buffers; bias+relu of previous layer)
    for (int j = tid; j < (KQ / 4) * MT; j += 512) {
        const int c  = j & (MT - 1);
        const int i4 = j / MT;
        float4 x = make_float4(0.f, 0.f, 0.f, 0.f);
        if (c < cnt) {
            const int row = perm ? perm[p0 + c] : (p0 + c);
            const size_t off = (size_t)row * IN + kbase + i4 * 4;
            x = *(const float4*)(X + off);
            #pragma unroll
            for (int pb = 1; pb < XPARTS; ++pb) {
                const float4 xp = *(const float4*)(X + (size_t)pb * Bn * IN + off);
                x.x += xp.x; x.y += xp.y; x.z += xp.z; x.w += xp.w;
            }
            if (Bin) {
                const float4 b = *(const float4*)(Bin + (size_t)e * bin_estride + kbase + i4 * 4);
                x.x = fmaxf(x.x + b.x, 0.f); x.y = fmaxf(x.y + b.y, 0.f);
                x.z = fmaxf(x.z + b.z, 0.f); x.w = fmaxf(x.w + b.w, 0.f);
            }
        }
        sxT[(i4 * 4 + 0) * MT + c] = x.x;
        sxT[(i4 * 4 + 1) * MT + c] = x.y;
        sxT[(i4 * 4 + 2) * MT + c] = x.z;
        sxT[(i4 * 4 + 3) * MT + c] = x.w;
    }
    __syncthreads();

    const int wave = tid >> 6, lane = tid & 63;
    const int colb = blockIdx.y * CCH;
    const int col  = colb + lane * 4;
    const int k0   = wave * KCH;
    const float* We = W + (size_t)e * IN * OUT + (size_t)(kbase + k0) * OUT + col;

    float acc[MT][4];
    #pragma unroll
    for (int c = 0; c < MT; ++c) { acc[c][0]=0.f; acc[c][1]=0.f; acc[c][2]=0.f; acc[c][3]=0.f; }

    #pragma unroll 8
    for (int i = 0; i < KCH; ++i) {
        const float4 w = *(const float4*)(We + (size_t)i * OUT);
        const float* xr = &sxT[(k0 + i) * MT];
        const float4 xa = *(const float4*)xr;
        const float4 xb = *(const float4*)(xr + 4);
        const float xs[8] = {xa.x, xa.y, xa.z, xa.w, xb.x, xb.y, xb.z, xb.w};
        #pragma unroll
        for (int c = 0; c < 8; ++c) {
            acc[c][0] = fmaf(xs[c], w.x, acc[c][0]);
            acc[c][1] = fmaf(xs[c], w.y, acc[c][1]);
            acc[c][2] = fmaf(xs[c], w.z, acc[c][2]);
            acc[c][3] = fmaf(xs[c], w.w, acc[c][3]);
        }
    }

    // LDS partial reduce: waves 0-3 write, 4-7 fold
    if (wave < NR) {
        #pragma unroll
        for (int c = 0; c < MT; ++c)
            *(float4*)&part[((wave * MT) + c) * CCH + lane * 4] = *(const float4*)acc[c];
    }
    __syncthreads();
    if (wave >= NR) {
        #pragma unroll
        for (int c = 0; c < MT; ++c) {
            float4* pp = (float4*)&part[(((wave - NR) * MT) + c) * CCH + lane * 4];
            float4 v = *pp;
            v.x += acc[c][0]; v.y += acc[c][1]; v.z += acc[c][2]; v.w += acc[c][3];
            *pp = v;
        }
    }
    __syncthreads();

    // final in-block reduce over 4 slots -> direct store into this quarter's buffer
    float* Yq = Y + (size_t)kq * Bn * OUT;
    for (int j = tid; j < MT * (CCH / 4); j += 512) {
        const int c = j / (CCH / 4);
        const int q = j % (CCH / 4);
        float4 s = *(const float4*)&part[c * CCH + q * 4];
        #pragma unroll
        for (int w = 1; w < NR; ++w) {
            const float4 p2 = *(const float4*)&part[((w * MT) + c) * CCH + q * 4];
            s.x += p2.x; s.y += p2.y; s.z += p2.z; s.w += p2.w;
        }
        if (c < cnt)
            *(float4*)(Yq + (size_t)(p0 + c) * OUT + colb + q * 4) = s;
    }
}

// ============ root L3 (512 -> 64) + argmax + lse + FUSED routing (last block) ============
// 4 samples per block -> 64 blocks. Input = h2 quarter-sums (4 parts); rb2+relu at staging.
__global__ __launch_bounds__(512) void root3_route(
        const float* __restrict__ H2, const float* __restrict__ Bin,
        const float* __restrict__ W, const float* __restrict__ bias,
        int* __restrict__ idx_out, float* __restrict__ rlp_out,
        int* __restrict__ perm, int4* __restrict__ groups, int* __restrict__ ctr) {
    __shared__ float sxT[Hm * 4];        // [i][c]
    __shared__ float part[8 * 4 * Em];
    __shared__ float fin[4][Em];
    __shared__ int sflag;
    __shared__ int cnt[Em];
    __shared__ int offs[Em];
    __shared__ int gtot;
    const int tid = threadIdx.x;
    const int b0 = blockIdx.x * 4;

    // stage: 512 j's = (Hm/4) i4-groups x 4 samples, one per thread
    {
        const int c = tid & 3, i4 = tid >> 2;
        const size_t off = (size_t)(b0 + c) * Hm + i4 * 4;
        float4 x = *(const float4*)(H2 + off);
        #pragma unroll
        for (int pb = 1; pb < 4; ++pb) {
            const float4 xp = *(const float4*)(H2 + (size_t)pb * Bn * Hm + off);
            x.x += xp.x; x.y += xp.y; x.z += xp.z; x.w += xp.w;
        }
        const float4 b = *(const float4*)(Bin + i4 * 4);
        x.x = fmaxf(x.x + b.x, 0.f); x.y = fmaxf(x.y + b.y, 0.f);
        x.z = fmaxf(x.z + b.z, 0.f); x.w = fmaxf(x.w + b.w, 0.f);
        sxT[(i4 * 4 + 0) * 4 + c] = x.x;
        sxT[(i4 * 4 + 1) * 4 + c] = x.y;
        sxT[(i4 * 4 + 2) * 4 + c] = x.z;
        sxT[(i4 * 4 + 3) * 4 + c] = x.w;
    }
    __syncthreads();

    const int wave = tid >> 6, lane = tid & 63;
    {   // 8 waves split K=512 into 64-chunks; lane = output col
        const int k0 = wave * 64;
        float acc[4] = {0.f, 0.f, 0.f, 0.f};
        #pragma unroll 8
        for (int i = 0; i < 64; ++i) {
            const float w = W[(size_t)(k0 + i) * Em + lane];
            const float4 xa = *(const float4*)&sxT[(k0 + i) * 4];
            acc[0] = fmaf(xa.x, w, acc[0]); acc[1] = fmaf(xa.y, w, acc[1]);
            acc[2] = fmaf(xa.z, w, acc[2]); acc[3] = fmaf(xa.w, w, acc[3]);
        }
        #pragma unroll
        for (int c = 0; c < 4; ++c) part[(wave * 4 + c) * Em + lane] = acc[c];
    }
    __syncthreads();

    if (tid < 256) {   // 4 samples x 64 cols: sum 8 wave slots + bias
        const int c = tid >> 6, colj = tid & 63;
        float s = bias[colj];
        #pragma unroll
        for (int w = 0; w < 8; ++w) s += part[(w * 4 + c) * Em + colj];
        fin[c][colj] = s;
    }
    __syncthreads();

    if (tid < 256) {   // wave c handles sample c: argmax (tie -> smaller idx) + lse
        const int c = wave;
        const float a0 = fin[c][lane];
        float v = a0; int bi = lane;
        #pragma unroll
        for (int off = 32; off; off >>= 1) {
            const float ov = __shfl_xor(v, off);
            const int   oi = __shfl_xor(bi, off);
            if (ov > v || (ov == v && oi < bi)) { v = ov; bi = oi; }
        }
        float ssum = expf(a0 - v);
        #pragma unroll
        for (int off = 32; off; off >>= 1) ssum += __shfl_xor(ssum, off);
        if (lane == 0) { idx_out[b0 + c] = bi; rlp_out[b0 + c] = -logf(ssum); }
    }

    // -------- fused routing: last finished block builds perm + groups --------
    __syncthreads();               // block's idx/rlp stores program-ordered
    __threadfence();               // release to device scope
    __syncthreads();
    if (tid == 0) sflag = (atomicAdd(ctr, 1) == (int)gridDim.x - 1);
    __syncthreads();
    if (sflag) {
        __threadfence();           // acquire: other blocks' idx stores now visible
        if (tid < Em) cnt[tid] = 0;
        __syncthreads();
        int e = -1, r = -1;
        if (tid < Bn) { e = idx_out[tid]; r = atomicAdd(&cnt[e], 1); }
        __syncthreads();
        if (tid < Em) {   // wave 0: dual inclusive scan (samples, groups)
            const int n  = cnt[tid];
            const int ng = (n + GS - 1) / GS;
            int s1 = n, s2 = ng;
            #pragma unroll
            for (int off = 1; off < 64; off <<= 1) {
                const int t1 = __shfl_up(s1, off);
                const int t2 = __shfl_up(s2, off);
                if (tid >= off) { s1 += t1; s2 += t2; }
            }
            offs[tid] = s1 - n;            // exclusive sample offset
            if (tid == Em - 1) gtot = s2;
            const int gb = s2 - ng;        // exclusive group offset
            for (int k = 0; k < ng; ++k)
                groups[gb + k] = make_int4(tid, (s1 - n) + k * GS, min(GS, n - k * GS), 0);
        }
        __syncthreads();
        for (int g = gtot + tid; g < MAXG; g += 512) groups[g] = make_int4(0, 0, 0, 0);
        if (tid < Bn) perm[offs[e] + r] = tid;
    }
}

// ============ log-softmax + top-11 + filter + outputs (4 logit quarters + eb3) ============
__global__ __launch_bounds__(512) void topk_kernel(
        const float* __restrict__ logitsQ, const float* __restrict__ eb3,
        const int* __restrict__ perm, const int* __restrict__ idx,
        const float* __restrict__ rlp, float* __restrict__ out) {
    __shared__ float sl[NL];
    __shared__ float redA[8];
    __shared__ float redB[8];
    __shared__ float bcast[2];
    const int p = blockIdx.x;
    const int tid = threadIdx.x;
    const int b = perm[p];
    const int e = idx[b];

    const size_t off = (size_t)p * NL + tid * 2;
    float2 v2 = *(const float2*)(logitsQ + off);
    #pragma unroll
    for (int pb = 1; pb < 4; ++pb) {
        const float2 vp = *(const float2*)(logitsQ + (size_t)pb * Bn * NL + off);
        v2.x += vp.x; v2.y += vp.y;
    }
    const float2 b2 = *(const float2*)(eb3 + (size_t)e * NL + tid * 2);
    v2.x += b2.x; v2.y += b2.y;
    sl[tid * 2] = v2.x; sl[tid * 2 + 1] = v2.y;

    float m = fmaxf(v2.x, v2.y);
    #pragma unroll
    for (int off2 = 32; off2; off2 >>= 1) m = fmaxf(m, __shfl_xor(m, off2));
    const int wave = tid >> 6;
    if ((tid & 63) == 0) redA[wave] = m;
    __syncthreads();
    if (tid == 0) {
        float mm = redA[0];
        #pragma unroll
        for (int w = 1; w < 8; ++w) mm = fmaxf(mm, redA[w]);
        bcast[0] = mm;
    }
    __syncthreads();
    m = bcast[0];

    float s = expf(v2.x - m) + expf(v2.y - m);
    #pragma unroll
    for (int off2 = 32; off2; off2 >>= 1) s += __shfl_xor(s, off2);
    if ((tid & 63) == 0) redB[wave] = s;
    __syncthreads();
    if (tid == 0) {
        float ss = 0.f;
        #pragma unroll
        for (int w = 0; w < 8; ++w) ss += redB[w];
        bcast[1] = m + logf(ss);
    }
    __syncthreads();
    const float logZ = bcast[1];

    if (tid < 64) {
        float vals[16];
        #pragma unroll
        for (int q = 0; q < 16; ++q) vals[q] = sl[tid * 16 + q];
        float selv[11];
        int   seli[11];
        for (int t = 0; t < 11; ++t) {
            float v = -INFINITY; int bq = 0;
            #pragma unroll
            for (int q = 0; q < 16; ++q) {
                if (vals[q] > v) { v = vals[q]; bq = q; }  // first occurrence on ties
            }
            int gi = tid * 16 + bq;
            #pragma unroll
            for (int off2 = 32; off2; off2 >>= 1) {
                const float ov = __shfl_xor(v, off2);
                const int   oi = __shfl_xor(gi, off2);
                if (ov > v || (ov == v && oi < gi)) { v = ov; gi = oi; }
            }
            selv[t] = v;
            seli[t] = gi;
            if ((gi >> 4) == tid) vals[gi & 15] = -INFINITY;
        }
        if (tid == 0) {
            const float rl = rlp[b];
            int c2 = 0;
            for (int t = 0; t < 11 && c2 < TOPK; ++t) {
                if (seli[t] == 0 && e == 0) continue;  // drop the (0,0) trajectory
                out[(b * TOPK + c2) * 2 + 0] = (float)e;
                out[(b * TOPK + c2) * 2 + 1] = (float)seli[t];
                out[Bn * TOPK * 2 + b * TOPK + c2] = selv[t] - logZ + rl;
                ++c2;
            }
        }
    }
}

extern "C" void kernel_launch(void* const* d_in, const int* in_sizes, int n_in,
                              void* d_out, int out_size, void* d_ws, size_t ws_size,
                              hipStream_t stream) {
    const float* state = (const float*)d_in[0];
    const float* rW1   = (const float*)d_in[1];
    const float* rb1   = (const float*)d_in[2];
    const float* rW2   = (const float*)d_in[3];
    const float* rb2   = (const float*)d_in[4];
    const float* rW3   = (const float*)d_in[5];
    const float* rb3   = (const float*)d_in[6];
    const float* eW1   = (const float*)d_in[7];
    const float* eb1   = (const float*)d_in[8];
    const float* eW2   = (const float*)d_in[9];
    const float* eb2   = (const float*)d_in[10];
    const float* eW3   = (const float*)d_in[11];
    const float* eb3   = (const float*)d_in[12];
    float* out = (float*)d_out;

    // quarter-sum buffer QUADS (contiguous: [q0][q1][q2][q3]), then control
    float* h1p    = (float*)d_ws;            // 4 x [256][512] root L1 quarters
    float* h2p    = h1p + 4 * Bn * Hm;       // 4 x [256][512] root L2 quarters
    float* eh1p   = h2p + 4 * Bn * Hm;       // 4 x [256][512] expert L1 quarters (permuted)
    float* eh2p   = eh1p + 4 * Bn * Hm;      // 4 x [256][512] expert L2 quarters (permuted)
    float* logp   = eh2p + 4 * Bn * Hm;      // 4 x [256][1024] expert L3 quarters (permuted)
    float* rlp    = logp + 4 * Bn * NL;      // [256]
    int*   idxp   = (int*)(rlp + Bn);        // [256]
    int*   perm   = idxp + Bn;               // [256]
    int4*  groups = (int4*)(perm + Bn);      // [88]
    int*   ctr    = (int*)(groups + MAXG);   // [1] root3 completion counter

    dense_ks4<Dm, Hm, 8, 1, false><<<dim3(Bn / 8, Hm / 256, 4), 512, 0, stream>>>(
        state, nullptr, nullptr, 0, rW1, nullptr, ctr, h1p);
    dense_ks4<Hm, Hm, 8, 4, false><<<dim3(Bn / 8, Hm / 256, 4), 512, 0, stream>>>(
        h1p, nullptr, rb1, 0, rW2, nullptr, nullptr, h2p);
    root3_route<<<Bn / 4, 512, 0, stream>>>(h2p, rb2, rW3, rb3, idxp, rlp,
                                            perm, groups, ctr);
    dense_ks4<Dm, Hm, 8, 1, true><<<dim3(MAXG, Hm / 256, 4), 512, 0, stream>>>(
        state, perm, nullptr, 0, eW1, groups, nullptr, eh1p);
    dense_ks4<Hm, Hm, 8, 4, true><<<dim3(MAXG, Hm / 256, 4), 512, 0, stream>>>(
        eh1p, nullptr, eb1, Hm, eW2, groups, nullptr, eh2p);
    dense_ks4<Hm, NL, 8, 4, true><<<dim3(MAXG, NL / 256, 4), 512, 0, stream>>>(
        eh2p, nullptr, eb2, Hm, eW3, groups, nullptr, logp);
    topk_kernel<<<Bn, 512, 0, stream>>>(logp, eb3, perm, idxp, rlp, out);
}

// Round 9
// 88.698 us; speedup vs baseline: 1.0055x; 1.0055x over previous
//
#include <hip/hip_runtime.h>
#include <math.h>

#define Bn 256
#define Dm 256
#define Hm 512
#define Em 64
#define NL 1024
#define TOPK 10
#define GS 8          // samples per expert group
#define MAXG 88       // max groups: 64 + (256-64)/8

// ============ K-split x4 dense: blockIdx.z = K-quarter -> writes its OWN buffer ============
// Y quarter buffers contiguous: Y + kq*Bn*OUT. Consumers add the 4 quarters.
// Input X has XPARTS part-buffers (stride Bn*IN) added at staging, with optional
// bias+relu of the previous layer (Bin != nullptr). zctr: if non-null, block (0,0,0)
// re-zeroes the root3 completion counter (device-scope atomic store).
template<int IN, int OUT, int MT, int XPARTS, bool GROUPED>
__global__ __launch_bounds__(512) void dense_ks4(
        const float* __restrict__ X, const int* __restrict__ perm,
        const float* __restrict__ Bin, int bin_estride,
        const float* __restrict__ W, const int4* __restrict__ groups,
        int* zctr, float* __restrict__ Y) {
    constexpr int NW = 8, KQ = IN / 4, KCH = KQ / NW, CCH = 256, NR = 4;

    if (zctr && threadIdx.x == 0 && blockIdx.x == 0 && blockIdx.y == 0 && blockIdx.z == 0)
        atomicExch(zctr, 0);

    int e, p0, cnt;
    if (GROUPED) {
        const int4 g = groups[blockIdx.x];
        if (g.z == 0) return;
        e = g.x; p0 = g.y; cnt = g.z;
    } else {
        e = 0; p0 = blockIdx.x * MT; cnt = MT;
    }
    const int kq = blockIdx.z;          // 0..3
    const int kbase = kq * KQ;

    __shared__ float sxT[KQ * MT];      // [local i][c]
    __shared__ float part[NR * MT * CCH];
    const int tid = threadIdx.x;

    // stage activations (sum XPARTS part-buffers; bias+relu of previous layer)
    for (int j = tid; j < (KQ / 4) * MT; j += 512) {
        const int c  = j & (MT - 1);
        const int i4 = j / MT;
        float4 x = make_float4(0.f, 0.f, 0.f, 0.f);
        if (c < cnt) {
            const int row = perm ? perm[p0 + c] : (p0 + c);
            const size_t off = (size_t)row * IN + kbase + i4 * 4;
            x = *(const float4*)(X + off);
            #pragma unroll
            for (int pb = 1; pb < XPARTS; ++pb) {
                const float4 xp = *(const float4*)(X + (size_t)pb * Bn * IN + off);
                x.x += xp.x; x.y += xp.y; x.z += xp.z; x.w += xp.w;
            }
            if (Bin) {
                const float4 b = *(const float4*)(Bin + (size_t)e * bin_estride + kbase + i4 * 4);
                x.x = fmaxf(x.x + b.x, 0.f); x.y = fmaxf(x.y + b.y, 0.f);
                x.z = fmaxf(x.z + b.z, 0.f); x.w = fmaxf(x.w + b.w, 0.f);
            }
        }
        sxT[(i4 * 4 + 0) * MT + c] = x.x;
        sxT[(i4 * 4 + 1) * MT + c] = x.y;
        sxT[(i4 * 4 + 2) * MT + c] = x.z;
        sxT[(i4 * 4 + 3) * MT + c] = x.w;
    }
    __syncthreads();

    const int wave = tid >> 6, lane = tid & 63;
    const int colb = blockIdx.y * CCH;
    const int col  = colb + lane * 4;
    const int k0   = wave * KCH;
    const float* We = W + (size_t)e * IN * OUT + (size_t)(kbase + k0) * OUT + col;

    float acc[MT][4];
    #pragma unroll
    for (int c = 0; c < MT; ++c) { acc[c][0]=0.f; acc[c][1]=0.f; acc[c][2]=0.f; acc[c][3]=0.f; }

    #pragma unroll 4
    for (int i = 0; i < KCH; ++i) {
        const float4 w = *(const float4*)(We + (size_t)i * OUT);
        const float* xr = &sxT[(k0 + i) * MT];
        const float4 xa = *(const float4*)xr;
        const float4 xb = *(const float4*)(xr + 4);
        const float xs[8] = {xa.x, xa.y, xa.z, xa.w, xb.x, xb.y, xb.z, xb.w};
        #pragma unroll
        for (int c = 0; c < 8; ++c) {
            acc[c][0] = fmaf(xs[c], w.x, acc[c][0]);
            acc[c][1] = fmaf(xs[c], w.y, acc[c][1]);
            acc[c][2] = fmaf(xs[c], w.z, acc[c][2]);
            acc[c][3] = fmaf(xs[c], w.w, acc[c][3]);
        }
    }

    // LDS partial reduce: waves 0-3 write, 4-7 fold
    if (wave < NR) {
        #pragma unroll
        for (int c = 0; c < MT; ++c)
            *(float4*)&part[((wave * MT) + c) * CCH + lane * 4] = *(const float4*)acc[c];
    }
    __syncthreads();
    if (wave >= NR) {
        #pragma unroll
        for (int c = 0; c < MT; ++c) {
            float4* pp = (float4*)&part[(((wave - NR) * MT) + c) * CCH + lane * 4];
            float4 v = *pp;
            v.x += acc[c][0]; v.y += acc[c][1]; v.z += acc[c][2]; v.w += acc[c][3];
            *pp = v;
        }
    }
    __syncthreads();

    // final in-block reduce over 4 slots -> direct store into this quarter's buffer
    float* Yq = Y + (size_t)kq * Bn * OUT;
    for (int j = tid; j < MT * (CCH / 4); j += 512) {
        const int c = j / (CCH / 4);
        const int q = j % (CCH / 4);
        float4 s = *(const float4*)&part[c * CCH + q * 4];
        #pragma unroll
        for (int w = 1; w < NR; ++w) {
            const float4 p2 = *(const float4*)&part[((w * MT) + c) * CCH + q * 4];
            s.x += p2.x; s.y += p2.y; s.z += p2.z; s.w += p2.w;
        }
        if (c < cnt)
            *(float4*)(Yq + (size_t)(p0 + c) * OUT + colb + q * 4) = s;
    }
}

// ============ root L3 (512 -> 64) + argmax + lse + FUSED routing (last block) ============
// 4 samples per block -> 64 blocks. Input = h2 quarter-sums (4 parts); rb2+relu at staging.
__global__ __launch_bounds__(512) void root3_route(
        const float* __restrict__ H2, const float* __restrict__ Bin,
        const float* __restrict__ W, const float* __restrict__ bias,
        int* __restrict__ idx_out, float* __restrict__ rlp_out,
        int* __restrict__ perm, int4* __restrict__ groups, int* __restrict__ ctr) {
    __shared__ float sxT[Hm * 4];        // [i][c]
    __shared__ float part[8 * 4 * Em];
    __shared__ float fin[4][Em];
    __shared__ int sflag;
    __shared__ int cnt[Em];
    __shared__ int offs[Em];
    __shared__ int gtot;
    const int tid = threadIdx.x;
    const int b0 = blockIdx.x * 4;

    // stage: 512 j's = (Hm/4) i4-groups x 4 samples, one per thread
    {
        const int c = tid & 3, i4 = tid >> 2;
        const size_t off = (size_t)(b0 + c) * Hm + i4 * 4;
        float4 x = *(const float4*)(H2 + off);
        #pragma unroll
        for (int pb = 1; pb < 4; ++pb) {
            const float4 xp = *(const float4*)(H2 + (size_t)pb * Bn * Hm + off);
            x.x += xp.x; x.y += xp.y; x.z += xp.z; x.w += xp.w;
        }
        const float4 b = *(const float4*)(Bin + i4 * 4);
        x.x = fmaxf(x.x + b.x, 0.f); x.y = fmaxf(x.y + b.y, 0.f);
        x.z = fmaxf(x.z + b.z, 0.f); x.w = fmaxf(x.w + b.w, 0.f);
        sxT[(i4 * 4 + 0) * 4 + c] = x.x;
        sxT[(i4 * 4 + 1) * 4 + c] = x.y;
        sxT[(i4 * 4 + 2) * 4 + c] = x.z;
        sxT[(i4 * 4 + 3) * 4 + c] = x.w;
    }
    __syncthreads();

    const int wave = tid >> 6, lane = tid & 63;
    {   // 8 waves split K=512 into 64-chunks; lane = output col
        const int k0 = wave * 64;
        float acc[4] = {0.f, 0.f, 0.f, 0.f};
        #pragma unroll 4
        for (int i = 0; i < 64; ++i) {
            const float w = W[(size_t)(k0 + i) * Em + lane];
            const float4 xa = *(const float4*)&sxT[(k0 + i) * 4];
            acc[0] = fmaf(xa.x, w, acc[0]); acc[1] = fmaf(xa.y, w, acc[1]);
            acc[2] = fmaf(xa.z, w, acc[2]); acc[3] = fmaf(xa.w, w, acc[3]);
        }
        #pragma unroll
        for (int c = 0; c < 4; ++c) part[(wave * 4 + c) * Em + lane] = acc[c];
    }
    __syncthreads();

    if (tid < 256) {   // 4 samples x 64 cols: sum 8 wave slots + bias
        const int c = tid >> 6, colj = tid & 63;
        float s = bias[colj];
        #pragma unroll
        for (int w = 0; w < 8; ++w) s += part[(w * 4 + c) * Em + colj];
        fin[c][colj] = s;
    }
    __syncthreads();

    if (tid < 256) {   // wave c handles sample c: argmax (tie -> smaller idx) + lse
        const int c = wave;
        const float a0 = fin[c][lane];
        float v = a0; int bi = lane;
        #pragma unroll
        for (int off = 32; off; off >>= 1) {
            const float ov = __shfl_xor(v, off);
            const int   oi = __shfl_xor(bi, off);
            if (ov > v || (ov == v && oi < bi)) { v = ov; bi = oi; }
        }
        float ssum = expf(a0 - v);
        #pragma unroll
        for (int off = 32; off; off >>= 1) ssum += __shfl_xor(ssum, off);
        if (lane == 0) { idx_out[b0 + c] = bi; rlp_out[b0 + c] = -logf(ssum); }
    }

    // -------- fused routing: last finished block builds perm + groups --------
    __syncthreads();               // block's idx/rlp stores program-ordered
    __threadfence();               // release to device scope
    __syncthreads();
    if (tid == 0) sflag = (atomicAdd(ctr, 1) == (int)gridDim.x - 1);
    __syncthreads();
    if (sflag) {
        __threadfence();           // acquire: other blocks' idx stores now visible
        if (tid < Em) cnt[tid] = 0;
        __syncthreads();
        int e = -1, r = -1;
        if (tid < Bn) { e = idx_out[tid]; r = atomicAdd(&cnt[e], 1); }
        __syncthreads();
        if (tid < Em) {   // wave 0: dual inclusive scan (samples, groups)
            const int n  = cnt[tid];
            const int ng = (n + GS - 1) / GS;
            int s1 = n, s2 = ng;
            #pragma unroll
            for (int off = 1; off < 64; off <<= 1) {
                const int t1 = __shfl_up(s1, off);
                const int t2 = __shfl_up(s2, off);
                if (tid >= off) { s1 += t1; s2 += t2; }
            }
            offs[tid] = s1 - n;            // exclusive sample offset
            if (tid == Em - 1) gtot = s2;
            const int gb = s2 - ng;        // exclusive group offset
            for (int k = 0; k < ng; ++k)
                groups[gb + k] = make_int4(tid, (s1 - n) + k * GS, min(GS, n - k * GS), 0);
        }
        __syncthreads();
        for (int g = gtot + tid; g < MAXG; g += 512) groups[g] = make_int4(0, 0, 0, 0);
        if (tid < Bn) perm[offs[e] + r] = tid;
    }
}

// ============ log-softmax + top-11 + filter + outputs (4 logit quarters + eb3) ============
__global__ __launch_bounds__(512) void topk_kernel(
        const float* __restrict__ logitsQ, const float* __restrict__ eb3,
        const int* __restrict__ perm, const int* __restrict__ idx,
        const float* __restrict__ rlp, float* __restrict__ out) {
    __shared__ float sl[NL];
    __shared__ float redA[8];
    __shared__ float redB[8];
    __shared__ float bcast[2];
    const int p = blockIdx.x;
    const int tid = threadIdx.x;
    const int b = perm[p];
    const int e = idx[b];

    const size_t off = (size_t)p * NL + tid * 2;
    float2 v2 = *(const float2*)(logitsQ + off);
    #pragma unroll
    for (int pb = 1; pb < 4; ++pb) {
        const float2 vp = *(const float2*)(logitsQ + (size_t)pb * Bn * NL + off);
        v2.x += vp.x; v2.y += vp.y;
    }
    const float2 b2 = *(const float2*)(eb3 + (size_t)e * NL + tid * 2);
    v2.x += b2.x; v2.y += b2.y;
    sl[tid * 2] = v2.x; sl[tid * 2 + 1] = v2.y;

    float m = fmaxf(v2.x, v2.y);
    #pragma unroll
    for (int off2 = 32; off2; off2 >>= 1) m = fmaxf(m, __shfl_xor(m, off2));
    const int wave = tid >> 6;
    if ((tid & 63) == 0) redA[wave] = m;
    __syncthreads();
    if (tid == 0) {
        float mm = redA[0];
        #pragma unroll
        for (int w = 1; w < 8; ++w) mm = fmaxf(mm, redA[w]);
        bcast[0] = mm;
    }
    __syncthreads();
    m = bcast[0];

    float s = expf(v2.x - m) + expf(v2.y - m);
    #pragma unroll
    for (int off2 = 32; off2; off2 >>= 1) s += __shfl_xor(s, off2);
    if ((tid & 63) == 0) redB[wave] = s;
    __syncthreads();
    if (tid == 0) {
        float ss = 0.f;
        #pragma unroll
        for (int w = 0; w < 8; ++w) ss += redB[w];
        bcast[1] = m + logf(ss);
    }
    __syncthreads();
    const float logZ = bcast[1];

    if (tid < 64) {
        float vals[16];
        #pragma unroll
        for (int q = 0; q < 16; ++q) vals[q] = sl[tid * 16 + q];
        float selv[11];
        int   seli[11];
        for (int t = 0; t < 11; ++t) {
            float v = -INFINITY; int bq = 0;
            #pragma unroll
            for (int q = 0; q < 16; ++q) {
                if (vals[q] > v) { v = vals[q]; bq = q; }  // first occurrence on ties
            }
            int gi = tid * 16 + bq;
            #pragma unroll
            for (int off2 = 32; off2; off2 >>= 1) {
                const float ov = __shfl_xor(v, off2);
                const int   oi = __shfl_xor(gi, off2);
                if (ov > v || (ov == v && oi < gi)) { v = ov; gi = oi; }
            }
            selv[t] = v;
            seli[t] = gi;
            if ((gi >> 4) == tid) vals[gi & 15] = -INFINITY;
        }
        if (tid == 0) {
            const float rl = rlp[b];
            int c2 = 0;
            for (int t = 0; t < 11 && c2 < TOPK; ++t) {
                if (seli[t] == 0 && e == 0) continue;  // drop the (0,0) trajectory
                out[(b * TOPK + c2) * 2 + 0] = (float)e;
                out[(b * TOPK + c2) * 2 + 1] = (float)seli[t];
                out[Bn * TOPK * 2 + b * TOPK + c2] = selv[t] - logZ + rl;
                ++c2;
            }
        }
    }
}

extern "C" void kernel_launch(void* const* d_in, const int* in_sizes, int n_in,
                              void* d_out, int out_size, void* d_ws, size_t ws_size,
                              hipStream_t stream) {
    const float* state = (const float*)d_in[0];
    const float* rW1   = (const float*)d_in[1];
    const float* rb1   = (const float*)d_in[2];
    const float* rW2   = (const float*)d_in[3];
    const float* rb2   = (const float*)d_in[4];
    const float* rW3   = (const float*)d_in[5];
    const float* rb3   = (const float*)d_in[6];
    const float* eW1   = (const float*)d_in[7];
    const float* eb1   = (const float*)d_in[8];
    const float* eW2   = (const float*)d_in[9];
    const float* eb2   = (const float*)d_in[10];
    const float* eW3   = (const float*)d_in[11];
    const float* eb3   = (const float*)d_in[12];
    float* out = (float*)d_out;

    // quarter-sum buffer QUADS (contiguous: [q0][q1][q2][q3]), then control
    float* h1p    = (float*)d_ws;            // 4 x [256][512] root L1 quarters
    float* h2p    = h1p + 4 * Bn * Hm;       // 4 x [256][512] root L2 quarters
    float* eh1p   = h2p + 4 * Bn * Hm;       // 4 x [256][512] expert L1 quarters (permuted)
    float* eh2p   = eh1p + 4 * Bn * Hm;      // 4 x [256][512] expert L2 quarters (permuted)
    float* logp   = eh2p + 4 * Bn * Hm;      // 4 x [256][1024] expert L3 quarters (permuted)
    float* rlp    = logp + 4 * Bn * NL;      // [256]
    int*   idxp   = (int*)(rlp + Bn);        // [256]
    int*   perm   = idxp + Bn;               // [256]
    int4*  groups = (int4*)(perm + Bn);      // [88]
    int*   ctr    = (int*)(groups + MAXG);   // [1] root3 completion counter

    dense_ks4<Dm, Hm, 8, 1, false><<<dim3(Bn / 8, Hm / 256, 4), 512, 0, stream>>>(
        state, nullptr, nullptr, 0, rW1, nullptr, ctr, h1p);
    dense_ks4<Hm, Hm, 8, 4, false><<<dim3(Bn / 8, Hm / 256, 4), 512, 0, stream>>>(
        h1p, nullptr, rb1, 0, rW2, nullptr, nullptr, h2p);
    root3_route<<<Bn / 4, 512, 0, stream>>>(h2p, rb2, rW3, rb3, idxp, rlp,
                                            perm, groups, ctr);
    dense_ks4<Dm, Hm, 8, 1, true><<<dim3(MAXG, Hm / 256, 4), 512, 0, stream>>>(
        state, perm, nullptr, 0, eW1, groups, nullptr, eh1p);
    dense_ks4<Hm, Hm, 8, 4, true><<<dim3(MAXG, Hm / 256, 4), 512, 0, stream>>>(
        eh1p, nullptr, eb1, Hm, eW2, groups, nullptr, eh2p);
    dense_ks4<Hm, NL, 8, 4, true><<<dim3(MAXG, NL / 256, 4), 512, 0, stream>>>(
        eh2p, nullptr, eb2, Hm, eW3, groups, nullptr, logp);
    topk_kernel<<<Bn, 512, 0, stream>>>(logp, eb3, perm, idxp, rlp, out);
}